// Round 2
// baseline (859.900 us; speedup 1.0000x reference)
//
#include <hip/hip_runtime.h>

// metaCLF: per-voxel MLP filter generation + filtering.
// x: [2,32,96^3] f32, d_all: [2,6,96^3] f32
// W1:[16,2] W2:[3,16] G1:[32,27] G2:[64,32] G3:[32,64]
// out: [2,1,96^3] f32
//
// Round 2: kill the h2[64] live range via reassociation:
//   out = sum_p h2[p] * w_p,  w_p = sum_c x_c * G3[c,p]
// x[32] is loaded once into regs; h2p/w_p are transient. Peak live ~80 VGPR
// -> no scratch spills (Round 1: VGPR=60 + spills -> 363us, 2x inst inflation).
// __launch_bounds__(256,5) caps VGPR at ~102 so the compiler can't
// spill-for-occupancy.

constexpr int V3   = 96 * 96 * 96;   // 884736
constexpr int NVOX = 2 * V3;         // 1769472

__global__ __launch_bounds__(256, 5) void metaclf_fused(
    const float* __restrict__ x,
    const float* __restrict__ d_all,
    const float* __restrict__ W1,
    const float* __restrict__ W2,
    const float* __restrict__ G1,
    const float* __restrict__ G2,
    const float* __restrict__ G3,
    float* __restrict__ out)
{
    const int idx = blockIdx.x * 256 + threadIdx.x;
    if (idx >= NVOX) return;
    const int b = (idx >= V3) ? 1 : 0;   // B=2: avoid integer divide
    const int v = idx - b * V3;

    // ---- load x channels once (32 regs, coalesced, stride V3) ----
    float xc[32];
#pragma unroll
    for (int c = 0; c < 32; ++c) xc[c] = x[(b * 32 + c) * V3 + v];

    // ---- encode: 2 -> 16 (relu) -> 3, for each of the 3 axes ----
    float e[3][3];
#pragma unroll
    for (int a = 0; a < 3; ++a) {
        const float d0 = d_all[(b * 6 + 2 * a    ) * V3 + v];
        const float d1 = d_all[(b * 6 + 2 * a + 1) * V3 + v];
        float a0 = 0.f, a1 = 0.f, a2 = 0.f;
#pragma unroll
        for (int k = 0; k < 16; ++k) {
            const float t = fmaxf(fmaf(W1[k * 2], d0, W1[k * 2 + 1] * d1), 0.f);
            a0 = fmaf(W2[0 * 16 + k], t, a0);
            a1 = fmaf(W2[1 * 16 + k], t, a1);
            a2 = fmaf(W2[2 * 16 + k], t, a2);
        }
        e[a][0] = a0; e[a][1] = a1; e[a][2] = a2;
    }

    // ---- G1 applied to kron(kron(ex,ey),ez) without materializing enced:
    //      h1[o] = relu( sum_{i,j,k} G1[o, i*9+j*3+k] * ex_i*ey_j*ez_k )
    // Build the 27 products (transient), then 32x27 MACs. ----
    float enced[27];
#pragma unroll
    for (int i = 0; i < 3; ++i)
#pragma unroll
        for (int j = 0; j < 3; ++j) {
            const float p = e[0][i] * e[1][j];
#pragma unroll
            for (int k = 0; k < 3; ++k)
                enced[i * 9 + j * 3 + k] = p * e[2][k];
        }

    float h1[32];
#pragma unroll
    for (int o = 0; o < 32; ++o) {
        float s = 0.f;
#pragma unroll
        for (int m = 0; m < 27; ++m) s = fmaf(G1[o * 27 + m], enced[m], s);
        h1[o] = fmaxf(s, 0.f);
    }

    // ---- fused G2/G3/dot: for each p, h2p and w_p are transient ----
    // h2p = relu(G2[p,:] . h1);  w_p = sum_c xc[c]*G3[c,p];  result += h2p*w_p
    float result = 0.f;
#pragma unroll
    for (int p = 0; p < 64; ++p) {
        float s = 0.f;
#pragma unroll
        for (int o = 0; o < 32; ++o) s = fmaf(G2[p * 32 + o], h1[o], s);
        const float h2p = fmaxf(s, 0.f);

        float w = 0.f;
#pragma unroll
        for (int c = 0; c < 32; ++c) w = fmaf(G3[c * 64 + p], xc[c], w);

        result = fmaf(h2p, w, result);
    }

    out[b * V3 + v] = result;
}

extern "C" void kernel_launch(void* const* d_in, const int* in_sizes, int n_in,
                              void* d_out, int out_size, void* d_ws, size_t ws_size,
                              hipStream_t stream) {
    const float* x     = (const float*)d_in[0];
    const float* d_all = (const float*)d_in[1];
    const float* W1    = (const float*)d_in[2];
    const float* W2    = (const float*)d_in[3];
    const float* G1    = (const float*)d_in[4];
    const float* G2    = (const float*)d_in[5];
    const float* G3    = (const float*)d_in[6];
    float* out = (float*)d_out;

    const int threads = 256;
    const int blocks  = (NVOX + threads - 1) / threads;
    metaclf_fused<<<blocks, threads, 0, stream>>>(x, d_all, W1, W2, G1, G2, G3, out);
}

// Round 3
// 570.460 us; speedup vs baseline: 1.5074x; 1.5074x over previous
//
#include <hip/hip_runtime.h>

// metaCLF: per-voxel MLP filter generation + filtering.
// x: [2,32,96^3] f32, d_all: [2,6,96^3] f32
// W1:[16,2] W2:[3,16] G1:[32,27] G2:[64,32] G3:[32,64]
// out: [2,1,96^3] f32
//
// Round 3: Round-2 reassociation (out = sum_p h2p * (G3^T x)_p) PLUS:
//  - amdgpu_waves_per_eu(4,4): pins allocator to 4 waves/EU -> 128 VGPR
//    budget. (R1/R2: allocator targeted 8+ waves -> 48-60 VGPR -> massive
//    scratch spills; R2 WRITE_SIZE showed ~70MB of spill traffic.)
//  - x[32] loaded AFTER h1 (only needed in p-loop) to shrink live range.
//  - no bounds check: NVOX = 6912 * 256 exactly.
//  - partial unroll (4) on big loops to stop load-hoisting register blowup.

constexpr int V3   = 96 * 96 * 96;   // 884736
constexpr int NVOX = 2 * V3;         // 1769472

__global__ __launch_bounds__(256)
__attribute__((amdgpu_waves_per_eu(4, 4)))
void metaclf_fused(
    const float* __restrict__ x,
    const float* __restrict__ d_all,
    const float* __restrict__ W1,
    const float* __restrict__ W2,
    const float* __restrict__ G1,
    const float* __restrict__ G2,
    const float* __restrict__ G3,
    float* __restrict__ out)
{
    const int idx = blockIdx.x * 256 + threadIdx.x;
    const int b = (idx >= V3) ? 1 : 0;   // B=2: avoid integer divide
    const int v = idx - b * V3;

    // ---- encode: 2 -> 16 (relu) -> 3, for each of the 3 axes ----
    float e[3][3];
#pragma unroll
    for (int a = 0; a < 3; ++a) {
        const float d0 = d_all[(b * 6 + 2 * a    ) * V3 + v];
        const float d1 = d_all[(b * 6 + 2 * a + 1) * V3 + v];
        float a0 = 0.f, a1 = 0.f, a2 = 0.f;
#pragma unroll
        for (int k = 0; k < 16; ++k) {
            const float t = fmaxf(fmaf(W1[k * 2], d0, W1[k * 2 + 1] * d1), 0.f);
            a0 = fmaf(W2[0 * 16 + k], t, a0);
            a1 = fmaf(W2[1 * 16 + k], t, a1);
            a2 = fmaf(W2[2 * 16 + k], t, a2);
        }
        e[a][0] = a0; e[a][1] = a1; e[a][2] = a2;
    }

    // ---- kron products (transient 27) ----
    float enced[27];
#pragma unroll
    for (int i = 0; i < 3; ++i)
#pragma unroll
        for (int j = 0; j < 3; ++j) {
            const float p = e[0][i] * e[1][j];
#pragma unroll
            for (int k = 0; k < 3; ++k)
                enced[i * 9 + j * 3 + k] = p * e[2][k];
        }

    // ---- G1: 27 -> 32, relu ----
    float h1[32];
#pragma unroll 4
    for (int o = 0; o < 32; ++o) {
        float s = 0.f;
#pragma unroll
        for (int m = 0; m < 27; ++m) s = fmaf(G1[o * 27 + m], enced[m], s);
        h1[o] = fmaxf(s, 0.f);
    }

    // ---- load x channels (only needed from here on) ----
    float xc[32];
#pragma unroll
    for (int c = 0; c < 32; ++c) xc[c] = x[(b * 32 + c) * V3 + v];

    // ---- fused G2/G3/dot: for each p, h2p and w_p are transient ----
    float result = 0.f;
#pragma unroll 4
    for (int p = 0; p < 64; ++p) {
        float s = 0.f;
#pragma unroll
        for (int o = 0; o < 32; ++o) s = fmaf(G2[p * 32 + o], h1[o], s);
        const float h2p = fmaxf(s, 0.f);

        float w = 0.f;
#pragma unroll
        for (int c = 0; c < 32; ++c) w = fmaf(G3[c * 64 + p], xc[c], w);

        result = fmaf(h2p, w, result);
    }

    out[b * V3 + v] = result;
}

extern "C" void kernel_launch(void* const* d_in, const int* in_sizes, int n_in,
                              void* d_out, int out_size, void* d_ws, size_t ws_size,
                              hipStream_t stream) {
    const float* x     = (const float*)d_in[0];
    const float* d_all = (const float*)d_in[1];
    const float* W1    = (const float*)d_in[2];
    const float* W2    = (const float*)d_in[3];
    const float* G1    = (const float*)d_in[4];
    const float* G2    = (const float*)d_in[5];
    const float* G3    = (const float*)d_in[6];
    float* out = (float*)d_out;

    const int threads = 256;
    const int blocks  = NVOX / threads;   // exact: 6912
    metaclf_fused<<<blocks, threads, 0, stream>>>(x, d_all, W1, W2, G1, G2, G3, out);
}

// Round 4
// 411.640 us; speedup vs baseline: 2.0890x; 1.3858x over previous
//
#include <hip/hip_runtime.h>

// metaCLF: per-voxel MLP filter generation + filtering. MFMA restructure.
// x: [2,32,96^3] f32, d_all: [2,6,96^3] f32
// W1:[16,2] W2:[3,16] G1:[32,27] G2:[64,32] G3:[32,64] -> out: [2,1,96^3] f32
//
// Round 4: per-thread scalar path is allocator-hostile (R1-R3: VGPR pinned at
// 48-60 with L2-resident scratch spills, 363-646us). Restructure:
//   - encode+kron in fp32 per thread (exact), scale by 2^14 (relu is
//     positively homogeneous -> scale passes through; final result * 2^-14),
//     convert to f16 into LDS.
//   - G1/G2/G3 as mfma_f32_16x16x32_f16, M=voxels. Each wave owns 64 voxels
//     (4 M-groups of 16); LDS round-trip between layers for C->A layout.
//   - final dot with x per-thread, coalesced fp32 loads.
// Fragment layouts (measured, learn_hip m89/m120):
//   A[m][k]: m = lane&15, k = (lane>>4)*8 + j
//   B[k][n]: n = lane&15, k = (lane>>4)*8 + j
//   C/D[m][n]: n = lane&15, m = (lane>>4)*4 + r

typedef _Float16 f16x8 __attribute__((ext_vector_type(8)));
typedef float    f32x4 __attribute__((ext_vector_type(4)));

constexpr int V3   = 96 * 96 * 96;   // 884736
constexpr int NVOX = 2 * V3;         // 1769472
constexpr int TV   = 256;            // voxels per block (V3 % TV == 0)
constexpr int NBLK = NVOX / TV;      // 6912

constexpr float SCALE     = 16384.f;      // 2^14
constexpr float INV_SCALE = 1.f / 16384.f;

// LDS row strides in f16 units; byte stride multiple of 16 (b128 alignment),
// not a multiple of 128B (bank spread).
constexpr int S32 = 40;   // rows of width 32 (E, H1, F): 80 B
constexpr int S64 = 72;   // rows of width 64 (H2): 144 B

__global__ __launch_bounds__(256) void metaclf_mfma(
    const float* __restrict__ x,
    const float* __restrict__ d_all,
    const float* __restrict__ W1,
    const float* __restrict__ W2,
    const float* __restrict__ G1,
    const float* __restrict__ G2,
    const float* __restrict__ G3,
    float* __restrict__ out)
{
    __shared__ _Float16 ldsA[TV * S64];  // phase 1-2: E (S32 rows); phase 3: H2 (S64 rows)
    __shared__ _Float16 ldsB[TV * S32];  // phase 2-3: H1; phase 4: F (filters)

    const int t    = threadIdx.x;
    const int lane = t & 63;
    const int wave = t >> 6;
    const int n16  = lane & 15;
    const int quad = lane >> 4;

    const int gidx = blockIdx.x * TV + t;
    const int b = (gidx >= V3) ? 1 : 0;      // uniform per block (V3 % TV == 0)
    const int v = gidx - b * V3;

    // ================= Phase 1: encode + kron (fp32, exact) -> E =================
    {
        float e[3][3];
#pragma unroll
        for (int a = 0; a < 3; ++a) {
            const float d0 = d_all[(b * 6 + 2 * a    ) * V3 + v];
            const float d1 = d_all[(b * 6 + 2 * a + 1) * V3 + v];
            float a0 = 0.f, a1 = 0.f, a2 = 0.f;
#pragma unroll
            for (int k = 0; k < 16; ++k) {
                const float tt = fmaxf(fmaf(W1[k * 2], d0, W1[k * 2 + 1] * d1), 0.f);
                a0 = fmaf(W2[0 * 16 + k], tt, a0);
                a1 = fmaf(W2[1 * 16 + k], tt, a1);
                a2 = fmaf(W2[2 * 16 + k], tt, a2);
            }
            e[a][0] = a0; e[a][1] = a1; e[a][2] = a2;
        }
        _Float16 row[32];
#pragma unroll
        for (int i = 0; i < 3; ++i)
#pragma unroll
            for (int j = 0; j < 3; ++j) {
                const float p = e[0][i] * e[1][j] * SCALE;
#pragma unroll
                for (int k = 0; k < 3; ++k)
                    row[i * 9 + j * 3 + k] = (_Float16)(p * e[2][k]);
            }
#pragma unroll
        for (int m = 27; m < 32; ++m) row[m] = (_Float16)0.f;

        f16x8* dst = (f16x8*)&ldsA[t * S32];
#pragma unroll
        for (int i = 0; i < 4; ++i) dst[i] = ((const f16x8*)row)[i];
    }
    __syncthreads();

    const int g0 = wave * 4;   // this wave's first 16-voxel group

    // ================= Phase 2: G1 (27->32), E -> H1 =================
    {
        f16x8 w0, w1;
#pragma unroll
        for (int j = 0; j < 8; ++j) {
            const int k = quad * 8 + j;
            w0[j] = (_Float16)((k < 27) ? G1[(n16     ) * 27 + k] : 0.f);
            w1[j] = (_Float16)((k < 27) ? G1[(16 + n16) * 27 + k] : 0.f);
        }
#pragma unroll
        for (int g = 0; g < 4; ++g) {
            const int rowv = (g0 + g) * 16;
            const f16x8 a = *(const f16x8*)&ldsA[(rowv + n16) * S32 + quad * 8];
            f32x4 c0 = {0.f, 0.f, 0.f, 0.f}, c1 = {0.f, 0.f, 0.f, 0.f};
            c0 = __builtin_amdgcn_mfma_f32_16x16x32_f16(a, w0, c0, 0, 0, 0);
            c1 = __builtin_amdgcn_mfma_f32_16x16x32_f16(a, w1, c1, 0, 0, 0);
#pragma unroll
            for (int r = 0; r < 4; ++r) {
                const int vr = rowv + quad * 4 + r;
                ldsB[vr * S32 + n16     ] = (_Float16)fmaxf(c0[r], 0.f);
                ldsB[vr * S32 + 16 + n16] = (_Float16)fmaxf(c1[r], 0.f);
            }
        }
    }
    __syncthreads();

    // ================= Phase 3: G2 (32->64), H1 -> H2 =================
    {
        f16x8 w[4];
#pragma unroll
        for (int q = 0; q < 4; ++q)
#pragma unroll
            for (int j = 0; j < 8; ++j)
                w[q][j] = (_Float16)G2[(q * 16 + n16) * 32 + quad * 8 + j];
#pragma unroll
        for (int g = 0; g < 4; ++g) {
            const int rowv = (g0 + g) * 16;
            const f16x8 a = *(const f16x8*)&ldsB[(rowv + n16) * S32 + quad * 8];
            f32x4 c[4];
#pragma unroll
            for (int q = 0; q < 4; ++q) {
                c[q] = (f32x4){0.f, 0.f, 0.f, 0.f};
                c[q] = __builtin_amdgcn_mfma_f32_16x16x32_f16(a, w[q], c[q], 0, 0, 0);
            }
#pragma unroll
            for (int r = 0; r < 4; ++r) {
                const int vr = rowv + quad * 4 + r;
#pragma unroll
                for (int q = 0; q < 4; ++q)
                    ldsA[vr * S64 + q * 16 + n16] = (_Float16)fmaxf(c[q][r], 0.f);
            }
        }
    }
    __syncthreads();

    // ================= Phase 4: G3 (64->32), H2 -> F (no relu) =================
    {
        f16x8 w[2][2];   // [k-half][n-half]
#pragma unroll
        for (int kh = 0; kh < 2; ++kh)
#pragma unroll
            for (int nh = 0; nh < 2; ++nh)
#pragma unroll
                for (int j = 0; j < 8; ++j)
                    w[kh][nh][j] = (_Float16)G3[(nh * 16 + n16) * 64 + kh * 32 + quad * 8 + j];
#pragma unroll
        for (int g = 0; g < 4; ++g) {
            const int rowv = (g0 + g) * 16;
            const f16x8 a0 = *(const f16x8*)&ldsA[(rowv + n16) * S64 + quad * 8];
            const f16x8 a1 = *(const f16x8*)&ldsA[(rowv + n16) * S64 + 32 + quad * 8];
            f32x4 c0 = {0.f, 0.f, 0.f, 0.f}, c1 = {0.f, 0.f, 0.f, 0.f};
            c0 = __builtin_amdgcn_mfma_f32_16x16x32_f16(a0, w[0][0], c0, 0, 0, 0);
            c0 = __builtin_amdgcn_mfma_f32_16x16x32_f16(a1, w[1][0], c0, 0, 0, 0);
            c1 = __builtin_amdgcn_mfma_f32_16x16x32_f16(a0, w[0][1], c1, 0, 0, 0);
            c1 = __builtin_amdgcn_mfma_f32_16x16x32_f16(a1, w[1][1], c1, 0, 0, 0);
#pragma unroll
            for (int r = 0; r < 4; ++r) {
                const int vr = rowv + quad * 4 + r;
                ldsB[vr * S32 + n16     ] = (_Float16)c0[r];
                ldsB[vr * S32 + 16 + n16] = (_Float16)c1[r];
            }
        }
    }
    __syncthreads();

    // ================= Phase 5: out = (x . filt) * 2^-14, coalesced =================
    {
        f16x8 frow[4];
#pragma unroll
        for (int i = 0; i < 4; ++i)
            frow[i] = *(const f16x8*)&ldsB[t * S32 + i * 8];

        const float* xb = x + (size_t)(b * 32) * V3 + v;
        float sum = 0.f;
#pragma unroll
        for (int c = 0; c < 32; ++c) {
            const float fc = (float)frow[c / 8][c % 8];
            sum = fmaf(xb[(size_t)c * V3], fc, sum);
        }
        out[b * V3 + v] = sum * INV_SCALE;
    }
}

extern "C" void kernel_launch(void* const* d_in, const int* in_sizes, int n_in,
                              void* d_out, int out_size, void* d_ws, size_t ws_size,
                              hipStream_t stream) {
    const float* x     = (const float*)d_in[0];
    const float* d_all = (const float*)d_in[1];
    const float* W1    = (const float*)d_in[2];
    const float* W2    = (const float*)d_in[3];
    const float* G1    = (const float*)d_in[4];
    const float* G2    = (const float*)d_in[5];
    const float* G3    = (const float*)d_in[6];
    float* out = (float*)d_out;

    metaclf_mfma<<<NBLK, 256, 0, stream>>>(x, d_all, W1, W2, G1, G2, G3, out);
}

// Round 5
// 352.437 us; speedup vs baseline: 2.4399x; 1.1680x over previous
//
#include <hip/hip_runtime.h>

// metaCLF: per-voxel MLP filter gen + filtering. MFMA, barrier-free.
// x: [2,32,96^3] f32, d_all: [2,6,96^3] f32
// W1:[16,2] W2:[3,16] G1:[32,27] G2:[64,32] G3:[32,64] -> out: [2,1,96^3] f32
//
// Round 5 (from R4's 177us, occupancy 22%, all pipes idle -> latency-bound):
//  - Each wave owns its 64 voxels end-to-end; LDS rows are wave-private.
//    DS ops are in-order within a wave -> NO __syncthreads needed; phases
//    separated by s_waitcnt lgkmcnt(0) + compiler memory clobber only.
//  - Single in-place LDS buffer, stride 72 f16 (144B; 16B-aligned, 4-dword
//    bank skew): E -> H1 -> H2 -> F(f32) all in place. 36.9 KB -> 4 blocks/CU.
//  - Weight B-fragments pre-packed to d_ws (f16, lane order) by a tiny pack
//    kernel: 10 coalesced b128 loads/wave replaces 80 scalar loads+cvt/thread.
//  - Scale 2^14 through the positively-homogeneous net (R4-validated,
//    absmax 1.9e-6 vs 8.1e-6 threshold).
// Fragment layouts (measured, learn_hip m89/m120):
//   A[m][k]: m=lane&15, k=(lane>>4)*8+j ; B[k][n]: n=lane&15, k=(lane>>4)*8+j
//   C/D[m][n]: n=lane&15, m=(lane>>4)*4+r

typedef _Float16 f16x8 __attribute__((ext_vector_type(8)));
typedef float    f32x4 __attribute__((ext_vector_type(4)));

constexpr int V3   = 96 * 96 * 96;   // 884736
constexpr int NVOX = 2 * V3;         // 1769472
constexpr int TV   = 256;            // voxels per block
constexpr int NBLK = NVOX / TV;      // 6912
constexpr int S    = 72;             // LDS row stride, f16 units (144 B)
constexpr int SD   = 36;             // same stride in f32 units

constexpr float SCALE     = 16384.f;
constexpr float INV_SCALE = 1.f / 16384.f;

// ws fragment table: 10 tiles x 64 lanes x 8 f16 = 10240 B
// tiles: 0,1 = G1 (nh) ; 2..5 = G2 (q) ; 6..9 = G3 (kh*2+nh)
constexpr int N_TILES  = 10;
constexpr int WS_BYTES = N_TILES * 64 * 8 * 2;

#define LDS_FENCE() asm volatile("s_waitcnt lgkmcnt(0)" ::: "memory")

__device__ __forceinline__ f16x8 build_frag(int tile, int n16, int quad,
                                            const float* __restrict__ G1,
                                            const float* __restrict__ G2,
                                            const float* __restrict__ G3) {
    f16x8 v;
    const int k0 = quad * 8;
#pragma unroll
    for (int j = 0; j < 8; ++j) {
        float f = 0.f;
        const int k = k0 + j;
        if (tile < 2) {
            if (k < 27) f = G1[(tile * 16 + n16) * 27 + k];
        } else if (tile < 6) {
            f = G2[((tile - 2) * 16 + n16) * 32 + k];
        } else {
            const int kh = (tile - 6) >> 1, nh = (tile - 6) & 1;
            f = G3[(nh * 16 + n16) * 64 + kh * 32 + k];
        }
        v[j] = (_Float16)f;
    }
    return v;
}

__global__ __launch_bounds__(256) void pack_weights(
    const float* __restrict__ G1, const float* __restrict__ G2,
    const float* __restrict__ G3, _Float16* __restrict__ wf)
{
    for (int slot = threadIdx.x; slot < N_TILES * 64; slot += 256) {
        const int tile = slot >> 6;
        const int lane = slot & 63;
        const f16x8 v = build_frag(tile, lane & 15, lane >> 4, G1, G2, G3);
        *(f16x8*)&wf[slot * 8] = v;
    }
}

template <bool USE_WS>
__global__ __launch_bounds__(256) void metaclf_mfma2(
    const float* __restrict__ x,
    const float* __restrict__ d_all,
    const float* __restrict__ W1,
    const float* __restrict__ W2,
    const float* __restrict__ G1,
    const float* __restrict__ G2,
    const float* __restrict__ G3,
    const _Float16* __restrict__ wf,
    float* __restrict__ out)
{
    __shared__ _Float16 lds[TV * S];           // 36,864 B
    float* const ldsf = (float*)lds;

    const int t    = threadIdx.x;
    const int lane = t & 63;
    const int wave = t >> 6;
    const int n16  = lane & 15;
    const int quad = lane >> 4;
    const int g0   = wave * 4;                 // first 16-voxel group of this wave

    const int gidx = blockIdx.x * TV + t;
    const int b = (gidx >= V3) ? 1 : 0;        // uniform per block
    const int v = gidx - b * V3;

    auto frag = [&](int tile) -> f16x8 {
        if constexpr (USE_WS) return *(const f16x8*)&wf[(tile * 64 + lane) * 8];
        else                  return build_frag(tile, n16, quad, G1, G2, G3);
    };

    // ========== Phase 1: encode + kron (fp32, exact), scaled -> E (f16) ==========
    {
        float e[3][3];
#pragma unroll
        for (int a = 0; a < 3; ++a) {
            const float d0 = d_all[(b * 6 + 2 * a    ) * V3 + v];
            const float d1 = d_all[(b * 6 + 2 * a + 1) * V3 + v];
            float a0 = 0.f, a1 = 0.f, a2 = 0.f;
#pragma unroll
            for (int k = 0; k < 16; ++k) {
                const float tt = fmaxf(fmaf(W1[k * 2], d0, W1[k * 2 + 1] * d1), 0.f);
                a0 = fmaf(W2[0 * 16 + k], tt, a0);
                a1 = fmaf(W2[1 * 16 + k], tt, a1);
                a2 = fmaf(W2[2 * 16 + k], tt, a2);
            }
            e[a][0] = a0; e[a][1] = a1; e[a][2] = a2;
        }
        _Float16 row[32];
#pragma unroll
        for (int i = 0; i < 3; ++i)
#pragma unroll
            for (int j = 0; j < 3; ++j) {
                const float p = e[0][i] * e[1][j] * SCALE;
#pragma unroll
                for (int k = 0; k < 3; ++k)
                    row[i * 9 + j * 3 + k] = (_Float16)(p * e[2][k]);
            }
#pragma unroll
        for (int m = 27; m < 32; ++m) row[m] = (_Float16)0.f;

        f16x8* dst = (f16x8*)&lds[t * S];
#pragma unroll
        for (int i = 0; i < 4; ++i) dst[i] = ((const f16x8*)row)[i];
    }
    LDS_FENCE();   // wave-local: own 64 rows fully written

    // ========== Phase 2: G1 (27->32), E -> H1, in place ==========
    {
        const f16x8 b0 = frag(0);
        const f16x8 b1 = frag(1);
#pragma unroll
        for (int g = 0; g < 4; ++g) {
            const int rowv = (g0 + g) * 16;
            const f16x8 a = *(const f16x8*)&lds[(rowv + n16) * S + quad * 8];
            f32x4 c0 = {0.f, 0.f, 0.f, 0.f}, c1 = {0.f, 0.f, 0.f, 0.f};
            c0 = __builtin_amdgcn_mfma_f32_16x16x32_f16(a, b0, c0, 0, 0, 0);
            c1 = __builtin_amdgcn_mfma_f32_16x16x32_f16(a, b1, c1, 0, 0, 0);
#pragma unroll
            for (int r = 0; r < 4; ++r) {
                const int vr = rowv + quad * 4 + r;
                lds[vr * S + n16     ] = (_Float16)fmaxf(c0[r], 0.f);
                lds[vr * S + 16 + n16] = (_Float16)fmaxf(c1[r], 0.f);
            }
        }
    }
    LDS_FENCE();

    // ========== Phase 3: G2 (32->64), H1 -> H2, in place ==========
    {
        f16x8 w[4];
#pragma unroll
        for (int q = 0; q < 4; ++q) w[q] = frag(2 + q);
#pragma unroll
        for (int g = 0; g < 4; ++g) {
            const int rowv = (g0 + g) * 16;
            const f16x8 a = *(const f16x8*)&lds[(rowv + n16) * S + quad * 8];
            f32x4 c[4];
#pragma unroll
            for (int q = 0; q < 4; ++q) {
                c[q] = (f32x4){0.f, 0.f, 0.f, 0.f};
                c[q] = __builtin_amdgcn_mfma_f32_16x16x32_f16(a, w[q], c[q], 0, 0, 0);
            }
#pragma unroll
            for (int r = 0; r < 4; ++r) {
                const int vr = rowv + quad * 4 + r;
#pragma unroll
                for (int q = 0; q < 4; ++q)
                    lds[vr * S + q * 16 + n16] = (_Float16)fmaxf(c[q][r], 0.f);
            }
        }
    }
    LDS_FENCE();

    // ========== Phase 4: G3 (64->32), H2 -> F (f32, no relu), in place ==========
    {
        const f16x8 w00 = frag(6), w01 = frag(7), w10 = frag(8), w11 = frag(9);
#pragma unroll
        for (int g = 0; g < 4; ++g) {
            const int rowv = (g0 + g) * 16;
            const f16x8 a0 = *(const f16x8*)&lds[(rowv + n16) * S + quad * 8];
            const f16x8 a1 = *(const f16x8*)&lds[(rowv + n16) * S + 32 + quad * 8];
            f32x4 c0 = {0.f, 0.f, 0.f, 0.f}, c1 = {0.f, 0.f, 0.f, 0.f};
            c0 = __builtin_amdgcn_mfma_f32_16x16x32_f16(a0, w00, c0, 0, 0, 0);
            c0 = __builtin_amdgcn_mfma_f32_16x16x32_f16(a1, w10, c0, 0, 0, 0);
            c1 = __builtin_amdgcn_mfma_f32_16x16x32_f16(a0, w01, c1, 0, 0, 0);
            c1 = __builtin_amdgcn_mfma_f32_16x16x32_f16(a1, w11, c1, 0, 0, 0);
#pragma unroll
            for (int r = 0; r < 4; ++r) {
                const int vr = rowv + quad * 4 + r;
                ldsf[vr * SD + n16     ] = c0[r];
                ldsf[vr * SD + 16 + n16] = c1[r];
            }
        }
    }
    LDS_FENCE();

    // ========== Phase 5: out = (x . F) * 2^-14, coalesced x loads ==========
    {
        const float* xb = x + (size_t)(b * 32) * V3 + v;
        float sum = 0.f;
#pragma unroll
        for (int i = 0; i < 8; ++i) {
            const f32x4 f = *(const f32x4*)&ldsf[t * SD + i * 4];
#pragma unroll
            for (int r = 0; r < 4; ++r)
                sum = fmaf(xb[(size_t)(i * 4 + r) * V3], f[r], sum);
        }
        out[b * V3 + v] = sum * INV_SCALE;
    }
}

extern "C" void kernel_launch(void* const* d_in, const int* in_sizes, int n_in,
                              void* d_out, int out_size, void* d_ws, size_t ws_size,
                              hipStream_t stream) {
    const float* x     = (const float*)d_in[0];
    const float* d_all = (const float*)d_in[1];
    const float* W1    = (const float*)d_in[2];
    const float* W2    = (const float*)d_in[3];
    const float* G1    = (const float*)d_in[4];
    const float* G2    = (const float*)d_in[5];
    const float* G3    = (const float*)d_in[6];
    float* out = (float*)d_out;

    if (ws_size >= (size_t)WS_BYTES) {
        _Float16* wf = (_Float16*)d_ws;
        pack_weights<<<1, 256, 0, stream>>>(G1, G2, G3, wf);
        metaclf_mfma2<true><<<NBLK, 256, 0, stream>>>(
            x, d_all, W1, W2, G1, G2, G3, wf, out);
    } else {
        metaclf_mfma2<false><<<NBLK, 256, 0, stream>>>(
            x, d_all, W1, W2, G1, G2, G3, nullptr, out);
    }
}

// Round 6
// 348.591 us; speedup vs baseline: 2.4668x; 1.0110x over previous
//
#include <hip/hip_runtime.h>

// metaCLF: per-voxel MLP filter gen + filtering. MFMA, barrier-free.
// x: [2,32,96^3] f32, d_all: [2,6,96^3] f32
// W1:[16,2] W2:[3,16] G1:[32,27] G2:[64,32] G3:[32,64] -> out: [2,1,96^3] f32
//
// Round 6 (from R5 kernel ~118us): swap MFMA operands: D = W * Act
// (M=out-channels, N=voxels). C/D layout (n=lane&15=voxel, m=quad*4+r=chan)
// puts a thread's 4 accumulator elems at 4 CONTIGUOUS channels of one voxel:
//   phase2: 2x ds_write_b64 (was 8x b16)   phase3: 4x b64 (was 16x b16)
//   phase4: 2x ds_write_b128 (was 8x b32)
// DS write pipe ~743 -> ~240 cyc/wave. Activation reads (B-frag: n=lane&15,
// k=quad*8+j) and the weight pack table (A-frag: m=lane&15, k=quad*8+j) are
// bit-identical to R5's -- only operand order + store indexing change.
// Everything else per R5: wave-private 64 voxels, no barriers (DS in-order
// within wave), single in-place LDS buffer (stride 72 f16), weights
// prepacked to d_ws, activations scaled 2^14 (relu pos-homogeneous).

typedef _Float16 f16x8 __attribute__((ext_vector_type(8)));
typedef _Float16 f16x4 __attribute__((ext_vector_type(4)));
typedef float    f32x4 __attribute__((ext_vector_type(4)));

constexpr int V3   = 96 * 96 * 96;   // 884736
constexpr int NVOX = 2 * V3;         // 1769472
constexpr int TV   = 256;            // voxels per block
constexpr int NBLK = NVOX / TV;      // 6912
constexpr int S    = 72;             // LDS row stride, f16 units (144 B)
constexpr int SD   = 36;             // same stride in f32 units

constexpr float SCALE     = 16384.f;
constexpr float INV_SCALE = 1.f / 16384.f;

// ws fragment table: 10 tiles x 64 lanes x 8 f16 = 10240 B
// tiles: 0,1 = G1 (m-half) ; 2..5 = G2 (m-quarter q) ; 6..9 = G3 (kh*2+mh)
constexpr int N_TILES  = 10;
constexpr int WS_BYTES = N_TILES * 64 * 8 * 2;

#define LDS_FENCE() asm volatile("s_waitcnt lgkmcnt(0)" ::: "memory")

__device__ __forceinline__ f16x8 build_frag(int tile, int n16, int quad,
                                            const float* __restrict__ G1,
                                            const float* __restrict__ G2,
                                            const float* __restrict__ G3) {
    f16x8 v;
    const int k0 = quad * 8;
#pragma unroll
    for (int j = 0; j < 8; ++j) {
        float f = 0.f;
        const int k = k0 + j;
        if (tile < 2) {
            if (k < 27) f = G1[(tile * 16 + n16) * 27 + k];
        } else if (tile < 6) {
            f = G2[((tile - 2) * 16 + n16) * 32 + k];
        } else {
            const int kh = (tile - 6) >> 1, nh = (tile - 6) & 1;
            f = G3[(nh * 16 + n16) * 64 + kh * 32 + k];
        }
        v[j] = (_Float16)f;
    }
    return v;
}

__global__ __launch_bounds__(256) void pack_weights(
    const float* __restrict__ G1, const float* __restrict__ G2,
    const float* __restrict__ G3, _Float16* __restrict__ wf)
{
    for (int slot = threadIdx.x; slot < N_TILES * 64; slot += 256) {
        const int tile = slot >> 6;
        const int lane = slot & 63;
        const f16x8 v = build_frag(tile, lane & 15, lane >> 4, G1, G2, G3);
        *(f16x8*)&wf[slot * 8] = v;
    }
}

template <bool USE_WS>
__global__ __launch_bounds__(256) void metaclf_mfma3(
    const float* __restrict__ x,
    const float* __restrict__ d_all,
    const float* __restrict__ W1,
    const float* __restrict__ W2,
    const float* __restrict__ G1,
    const float* __restrict__ G2,
    const float* __restrict__ G3,
    const _Float16* __restrict__ wf,
    float* __restrict__ out)
{
    __shared__ _Float16 lds[TV * S];           // 36,864 B
    float* const ldsf = (float*)lds;

    const int t    = threadIdx.x;
    const int lane = t & 63;
    const int wave = t >> 6;
    const int n16  = lane & 15;
    const int quad = lane >> 4;
    const int g0   = wave * 4;                 // first 16-voxel group of this wave

    const int gidx = blockIdx.x * TV + t;
    const int b = (gidx >= V3) ? 1 : 0;        // uniform per block
    const int v = gidx - b * V3;

    auto frag = [&](int tile) -> f16x8 {
        if constexpr (USE_WS) return *(const f16x8*)&wf[(tile * 64 + lane) * 8];
        else                  return build_frag(tile, n16, quad, G1, G2, G3);
    };

    // ========== Phase 1: encode + kron (fp32, exact), scaled -> E (f16) ==========
    {
        float e[3][3];
#pragma unroll
        for (int a = 0; a < 3; ++a) {
            const float d0 = d_all[(b * 6 + 2 * a    ) * V3 + v];
            const float d1 = d_all[(b * 6 + 2 * a + 1) * V3 + v];
            float a0 = 0.f, a1 = 0.f, a2 = 0.f;
#pragma unroll
            for (int k = 0; k < 16; ++k) {
                const float tt = fmaxf(fmaf(W1[k * 2], d0, W1[k * 2 + 1] * d1), 0.f);
                a0 = fmaf(W2[0 * 16 + k], tt, a0);
                a1 = fmaf(W2[1 * 16 + k], tt, a1);
                a2 = fmaf(W2[2 * 16 + k], tt, a2);
            }
            e[a][0] = a0; e[a][1] = a1; e[a][2] = a2;
        }
        _Float16 row[32];
#pragma unroll
        for (int i = 0; i < 3; ++i)
#pragma unroll
            for (int j = 0; j < 3; ++j) {
                const float p = e[0][i] * e[1][j] * SCALE;
#pragma unroll
                for (int k = 0; k < 3; ++k)
                    row[i * 9 + j * 3 + k] = (_Float16)(p * e[2][k]);
            }
#pragma unroll
        for (int m = 27; m < 32; ++m) row[m] = (_Float16)0.f;

        f16x8* dst = (f16x8*)&lds[t * S];
#pragma unroll
        for (int i = 0; i < 4; ++i) dst[i] = ((const f16x8*)row)[i];
    }
    LDS_FENCE();   // wave-local: own 64 rows fully written

    // ========== Phase 2: G1 (27->32), E -> H1, in place ==========
    // D = G1 * E^T : m = out-channel, n = voxel. Thread stores channels
    // [quad*4, quad*4+4) and [16+quad*4, ...) of voxel rowv+n16 as b64.
    {
        const f16x8 b0 = frag(0);
        const f16x8 b1 = frag(1);
#pragma unroll
        for (int g = 0; g < 4; ++g) {
            const int rowv = (g0 + g) * 16;
            const f16x8 a = *(const f16x8*)&lds[(rowv + n16) * S + quad * 8];
            f32x4 c0 = {0.f, 0.f, 0.f, 0.f}, c1 = {0.f, 0.f, 0.f, 0.f};
            c0 = __builtin_amdgcn_mfma_f32_16x16x32_f16(b0, a, c0, 0, 0, 0);
            c1 = __builtin_amdgcn_mfma_f32_16x16x32_f16(b1, a, c1, 0, 0, 0);
            f16x4 h0, h1;
#pragma unroll
            for (int r = 0; r < 4; ++r) {
                h0[r] = (_Float16)fmaxf(c0[r], 0.f);
                h1[r] = (_Float16)fmaxf(c1[r], 0.f);
            }
            *(f16x4*)&lds[(rowv + n16) * S + quad * 4]      = h0;
            *(f16x4*)&lds[(rowv + n16) * S + 16 + quad * 4] = h1;
        }
    }
    LDS_FENCE();

    // ========== Phase 3: G2 (32->64), H1 -> H2, in place ==========
    {
        f16x8 w[4];
#pragma unroll
        for (int q = 0; q < 4; ++q) w[q] = frag(2 + q);
#pragma unroll
        for (int g = 0; g < 4; ++g) {
            const int rowv = (g0 + g) * 16;
            const f16x8 a = *(const f16x8*)&lds[(rowv + n16) * S + quad * 8];
            f32x4 c[4];
#pragma unroll
            for (int q = 0; q < 4; ++q) {
                c[q] = (f32x4){0.f, 0.f, 0.f, 0.f};
                c[q] = __builtin_amdgcn_mfma_f32_16x16x32_f16(w[q], a, c[q], 0, 0, 0);
            }
#pragma unroll
            for (int q = 0; q < 4; ++q) {
                f16x4 h;
#pragma unroll
                for (int r = 0; r < 4; ++r) h[r] = (_Float16)fmaxf(c[q][r], 0.f);
                *(f16x4*)&lds[(rowv + n16) * S + q * 16 + quad * 4] = h;
            }
        }
    }
    LDS_FENCE();

    // ========== Phase 4: G3 (64->32), H2 -> F (f32, no relu), in place ==========
    {
        const f16x8 w00 = frag(6), w01 = frag(7), w10 = frag(8), w11 = frag(9);
#pragma unroll
        for (int g = 0; g < 4; ++g) {
            const int rowv = (g0 + g) * 16;
            const f16x8 a0 = *(const f16x8*)&lds[(rowv + n16) * S + quad * 8];
            const f16x8 a1 = *(const f16x8*)&lds[(rowv + n16) * S + 32 + quad * 8];
            f32x4 c0 = {0.f, 0.f, 0.f, 0.f}, c1 = {0.f, 0.f, 0.f, 0.f};
            c0 = __builtin_amdgcn_mfma_f32_16x16x32_f16(w00, a0, c0, 0, 0, 0);
            c0 = __builtin_amdgcn_mfma_f32_16x16x32_f16(w10, a1, c0, 0, 0, 0);
            c1 = __builtin_amdgcn_mfma_f32_16x16x32_f16(w01, a0, c1, 0, 0, 0);
            c1 = __builtin_amdgcn_mfma_f32_16x16x32_f16(w11, a1, c1, 0, 0, 0);
            // channels [quad*4, +4) and [16+quad*4, +4) of voxel rowv+n16, f32
            *(f32x4*)&ldsf[(rowv + n16) * SD + quad * 4]      = c0;
            *(f32x4*)&ldsf[(rowv + n16) * SD + 16 + quad * 4] = c1;
        }
    }
    LDS_FENCE();

    // ========== Phase 5: out = (x . F) * 2^-14, coalesced x loads ==========
    {
        const float* xb = x + (size_t)(b * 32) * V3 + v;
        float sum = 0.f;
#pragma unroll
        for (int i = 0; i < 8; ++i) {
            const f32x4 f = *(const f32x4*)&ldsf[t * SD + i * 4];
#pragma unroll
            for (int r = 0; r < 4; ++r)
                sum = fmaf(xb[(size_t)(i * 4 + r) * V3], f[r], sum);
        }
        out[b * V3 + v] = sum * INV_SCALE;
    }
}

extern "C" void kernel_launch(void* const* d_in, const int* in_sizes, int n_in,
                              void* d_out, int out_size, void* d_ws, size_t ws_size,
                              hipStream_t stream) {
    const float* x     = (const float*)d_in[0];
    const float* d_all = (const float*)d_in[1];
    const float* W1    = (const float*)d_in[2];
    const float* W2    = (const float*)d_in[3];
    const float* G1    = (const float*)d_in[4];
    const float* G2    = (const float*)d_in[5];
    const float* G3    = (const float*)d_in[6];
    float* out = (float*)d_out;

    if (ws_size >= (size_t)WS_BYTES) {
        _Float16* wf = (_Float16*)d_ws;
        pack_weights<<<1, 256, 0, stream>>>(G1, G2, G3, wf);
        metaclf_mfma3<true><<<NBLK, 256, 0, stream>>>(
            x, d_all, W1, W2, G1, G2, G3, wf, out);
    } else {
        metaclf_mfma3<false><<<NBLK, 256, 0, stream>>>(
            x, d_all, W1, W2, G1, G2, G3, nullptr, out);
    }
}